// Round 7
// baseline (237.970 us; speedup 1.0000x reference)
//
#include <hip/hip_runtime.h>
#include <hip/hip_bf16.h>

// B=4, N=1024, C=768, H=12, D=64, SCALE=1/8. Inputs fp32, output fp32.
// Internal math bf16 MFMA. fp32->bf16 pre-convert enables global_load_lds(16B).

typedef __bf16 bf16x8 __attribute__((ext_vector_type(8)));
typedef __bf16 bf16x4 __attribute__((ext_vector_type(4)));
typedef float  f32x4  __attribute__((ext_vector_type(4)));

__device__ __forceinline__ bf16x8 cvt8(const float* p) {
    f32x4 f0 = *(const f32x4*)p;
    f32x4 f1 = *(const f32x4*)(p + 4);
    bf16x8 r;
    r[0] = (__bf16)f0[0]; r[1] = (__bf16)f0[1]; r[2] = (__bf16)f0[2]; r[3] = (__bf16)f0[3];
    r[4] = (__bf16)f1[0]; r[5] = (__bf16)f1[1]; r[6] = (__bf16)f1[2]; r[7] = (__bf16)f1[3];
    return r;
}

__device__ __forceinline__ void async16(const __bf16* g, __bf16* l) {
    __builtin_amdgcn_global_load_lds(
        (const __attribute__((address_space(1))) void*)g,
        (__attribute__((address_space(3))) void*)l, 16, 0, 0);
}

// ---------------------------------------------------------------------------
// Fused front-end convert: x1 | x2 | Wqkv | (optionally Wproj) in ONE kernel.
// ---------------------------------------------------------------------------
__global__ __launch_bounds__(256)
void cvt4_k(const float* __restrict__ x1, const float* __restrict__ x2,
            const float* __restrict__ wq, const float* __restrict__ wp,
            __bf16* __restrict__ xc, __bf16* __restrict__ wqc,
            __bf16* __restrict__ wpc)
{
    int bid = blockIdx.x;
    const float* src; __bf16* dst; int i;
    if (bid < 1536)      { src = x1; dst = xc;             i = (bid * 256 + threadIdx.x) * 8; }
    else if (bid < 3072) { src = x2; dst = xc + 3145728;   i = ((bid - 1536) * 256 + threadIdx.x) * 8; }
    else if (bid < 3936) { src = wq; dst = wqc;            i = ((bid - 3072) * 256 + threadIdx.x) * 8; }
    else                 { src = wp; dst = wpc;            i = ((bid - 3936) * 256 + threadIdx.x) * 8; }
    *(bf16x8*)(dst + i) = cvt8(src + i);
}

__global__ __launch_bounds__(256)
void cvt_k(const float* __restrict__ src, __bf16* __restrict__ dst, int n) {
    int i = (blockIdx.x * 256 + threadIdx.x) * 8;
    if (i < n) *(bf16x8*)(dst + i) = cvt8(src + i);
}

// ---------------------------------------------------------------------------
// QKV GEMM, 128x128 tile, BK=32, 3-buffer counted-vmcnt pipeline (round-3
// structure, measured best) + K-MAJOR LDS RELAYOUT: within each 16-row x
// 32-col (1 KB) group, slot = kslot*16 + row. MFMA fragment reads become
// group_base + lane*16B -> perfectly sequential 1 KB per ds_read_b128 wave,
// ZERO bank conflicts (b128 floor = 8 cyc). Staging keeps the linear
// global_load_lds dest (uniform base + lane*16B) and pre-permutes only the
// GLOBAL source: row = lane&15, col = (lane>>4)*8 -- the per-instruction
// address set is unchanged (same 64B segments), so L2 traffic is identical.
// Race proof (one barrier/iter): writer at iter kt targets buf[(kt+1)%3];
// slowest reader uses buf[(kt-1)%3] - disjoint with 3 buffers.
// XCD-ownership swizzle: W hot in each XCD's L2.
// ---------------------------------------------------------------------------
__global__ __launch_bounds__(256)
void gemm_qkv_s(const __bf16* __restrict__ Xc, const __bf16* __restrict__ Wq,
                const float* __restrict__ bias,
                __bf16* __restrict__ qo, __bf16* __restrict__ ko,
                __bf16* __restrict__ vo)
{
    constexpr int K = 768;
    __shared__ __bf16 As[3][128 * 32];   // 24 KB
    __shared__ __bf16 Bs[3][128 * 32];   // 24 KB

    const int t = threadIdx.x, w = t >> 6, lane = t & 63;
    const int l15 = lane & 15, quad = lane >> 4;
    const int wm = w >> 1, wn = w & 1;

    // XCD-ownership decode: bid%8 = XCD; (gy,st) constant per (xcd,pair)
    const int bid  = blockIdx.x;          // 0..1151
    const int xcd  = bid & 7;
    const int i6   = bid >> 3;            // 0..143
    const int pair = i6 / 18;             // 0..7
    const int gx   = i6 - pair * 18;      // 0..17
    const int p    = xcd * 8 + pair;      // 0..63
    const int gy   = p & 31;
    const int st   = p >> 5;

    // staging (k-major groups): wave w owns rows [w*32, w*32+32)
    const int sgrp = w * 32;
    const int srow = lane & 15;           // row within 16-group
    const int scol = (lane >> 4) * 8;     // k-slot within BK=32

    const __bf16* Ab = Xc + (size_t)st * 3145728 + (size_t)(gy * 128) * K;
    const __bf16* Bb = Wq + (size_t)(gx * 128) * K;

    f32x4 acc[4][4];
#pragma unroll
    for (int mi = 0; mi < 4; mi++)
#pragma unroll
        for (int ni = 0; ni < 4; ni++) acc[mi][ni] = f32x4{0.f, 0.f, 0.f, 0.f};

#define QSTAGE(BUF, KT)                                                          \
    do {                                                                         \
        const int _k0 = (KT) * 32;                                               \
        async16(Ab + (size_t)(sgrp + srow) * K + _k0 + scol,                     \
                &As[BUF][sgrp * 32 + lane * 8]);                                 \
        async16(Ab + (size_t)(sgrp + 16 + srow) * K + _k0 + scol,                \
                &As[BUF][(sgrp + 16) * 32 + lane * 8]);                          \
        async16(Bb + (size_t)(sgrp + srow) * K + _k0 + scol,                     \
                &Bs[BUF][sgrp * 32 + lane * 8]);                                 \
        async16(Bb + (size_t)(sgrp + 16 + srow) * K + _k0 + scol,                \
                &Bs[BUF][(sgrp + 16) * 32 + lane * 8]);                          \
    } while (0)

    // prologue: stage K-step 0 into buf 0
    QSTAGE(0, 0);

#pragma unroll 3
    for (int kt = 0; kt < 24; kt++) {
        const int cb = kt % 3;
        if (kt < 23) {
            QSTAGE((kt + 1) % 3, kt + 1);
            asm volatile("s_waitcnt vmcnt(4)" ::: "memory");  // tile kt landed; kt+1 in flight
        } else {
            asm volatile("s_waitcnt vmcnt(0)" ::: "memory");  // tail: drain last tile
        }
        __builtin_amdgcn_s_barrier();
        __builtin_amdgcn_sched_barrier(0);

        bf16x8 af[4], bfr[4];
#pragma unroll
        for (int mi = 0; mi < 4; mi++)
            af[mi] = *(const bf16x8*)&As[cb][(wm * 64 + mi * 16) * 32 + lane * 8];
#pragma unroll
        for (int ni = 0; ni < 4; ni++)
            bfr[ni] = *(const bf16x8*)&Bs[cb][(wn * 64 + ni * 16) * 32 + lane * 8];
#pragma unroll
        for (int mi = 0; mi < 4; mi++)
#pragma unroll
            for (int ni = 0; ni < 4; ni++)
                acc[mi][ni] = __builtin_amdgcn_mfma_f32_16x16x32_bf16(af[mi], bfr[ni], acc[mi][ni], 0, 0, 0);
        // no trailing barrier: next iter's stage targets buf[(kt+2)%3],
        // disjoint from any buffer still being read (skew < 1 iter).
    }
#undef QSTAGE

    const int which = (gx * 128) / 768;   // uniform per block (tile never spans)

    if (which == 2) {
        // V: packed bf16x4 stores, 4 consecutive tokens (aligned, b-safe)
#pragma unroll
        for (int ni = 0; ni < 4; ni++) {
            int j = gx * 128 + wn * 64 + ni * 16 + l15;
            int c = j - 1536;
            int h = c >> 6, d = c & 63;
            float bj = bias[j];
#pragma unroll
            for (int mi = 0; mi < 4; mi++) {
                int row0 = gy * 128 + wm * 64 + mi * 16 + quad * 4;
                int b = row0 >> 10, tok0 = row0 & 1023;
                bf16x4 pv;
#pragma unroll
                for (int r = 0; r < 4; r++) pv[r] = (__bf16)(acc[mi][ni][r] + bj);
                *(bf16x4*)&vo[((size_t)((st * 4 + b) * 12 + h) * 64 + d) * 1024 + tok0] = pv;
            }
        }
    } else {
        // Q / K: lane-coalesced scalar stores (d consecutive across l15)
#pragma unroll
        for (int ni = 0; ni < 4; ni++) {
            int j     = gx * 128 + wn * 64 + ni * 16 + l15;   // 0..1535
            int c     = j - which * 768;
            int h = c >> 6, d = c & 63;
            float bj  = bias[j];
#pragma unroll
            for (int mi = 0; mi < 4; mi++) {
#pragma unroll
                for (int r = 0; r < 4; r++) {
                    int row = gy * 128 + wm * 64 + mi * 16 + quad * 4 + r;
                    int b = row >> 10, tok = row & 1023;
                    float val = acc[mi][ni][r] + bj;
                    if (which == 0)
                        qo[((size_t)((st * 4 + b) * 12 + h) * 1024 + tok) * 64 + d] = (__bf16)(val * 0.125f);
                    else
                        ko[((size_t)((st * 4 + b) * 12 + h) * 1024 + tok) * 64 + d] = (__bf16)val;
                }
            }
        }
    }
}

// ---------------------------------------------------------------------------
// 128x128-tile proj GEMM, BK=32, 3-buffer pipeline + same k-major LDS
// relayout (conflict-free b128 reads). A bf16 [8192x768], W bf16 [768x768].
// ---------------------------------------------------------------------------
__global__ __launch_bounds__(256)
void gemm_proj(const __bf16* __restrict__ A, const __bf16* __restrict__ Wp,
               const float* __restrict__ bias, float* __restrict__ out)
{
    constexpr int K = 768;
    __shared__ __bf16 As[3][128 * 32];
    __shared__ __bf16 Bs[3][128 * 32];

    const int t = threadIdx.x, w = t >> 6, lane = t & 63;
    const int l15 = lane & 15, quad = lane >> 4;
    const int wm = w >> 1, wn = w & 1;
    const int gx = blockIdx.x, gy = blockIdx.y;

    const int sgrp = w * 32;
    const int srow = lane & 15;
    const int scol = (lane >> 4) * 8;

    const __bf16* Ab = A  + (size_t)(gy * 128) * K;
    const __bf16* Bb = Wp + (size_t)(gx * 128) * K;

    f32x4 acc[4][4];
#pragma unroll
    for (int mi = 0; mi < 4; mi++)
#pragma unroll
        for (int ni = 0; ni < 4; ni++) acc[mi][ni] = f32x4{0.f, 0.f, 0.f, 0.f};

#define PSTAGE(BUF, KT)                                                          \
    do {                                                                         \
        const int _k0 = (KT) * 32;                                               \
        async16(Ab + (size_t)(sgrp + srow) * K + _k0 + scol,                     \
                &As[BUF][sgrp * 32 + lane * 8]);                                 \
        async16(Ab + (size_t)(sgrp + 16 + srow) * K + _k0 + scol,                \
                &As[BUF][(sgrp + 16) * 32 + lane * 8]);                          \
        async16(Bb + (size_t)(sgrp + srow) * K + _k0 + scol,                     \
                &Bs[BUF][sgrp * 32 + lane * 8]);                                 \
        async16(Bb + (size_t)(sgrp + 16 + srow) * K + _k0 + scol,                \
                &Bs[BUF][(sgrp + 16) * 32 + lane * 8]);                          \
    } while (0)

    PSTAGE(0, 0);

#pragma unroll 3
    for (int kt = 0; kt < 24; kt++) {
        const int cb = kt % 3;
        if (kt < 23) {
            PSTAGE((kt + 1) % 3, kt + 1);
            asm volatile("s_waitcnt vmcnt(4)" ::: "memory");
        } else {
            asm volatile("s_waitcnt vmcnt(0)" ::: "memory");
        }
        __builtin_amdgcn_s_barrier();
        __builtin_amdgcn_sched_barrier(0);

        bf16x8 af[4], bfr[4];
#pragma unroll
        for (int mi = 0; mi < 4; mi++)
            af[mi] = *(const bf16x8*)&As[cb][(wm * 64 + mi * 16) * 32 + lane * 8];
#pragma unroll
        for (int ni = 0; ni < 4; ni++)
            bfr[ni] = *(const bf16x8*)&Bs[cb][(wn * 64 + ni * 16) * 32 + lane * 8];
#pragma unroll
        for (int mi = 0; mi < 4; mi++)
#pragma unroll
            for (int ni = 0; ni < 4; ni++)
                acc[mi][ni] = __builtin_amdgcn_mfma_f32_16x16x32_bf16(af[mi], bfr[ni], acc[mi][ni], 0, 0, 0);
    }
#undef PSTAGE

#pragma unroll
    for (int ni = 0; ni < 4; ni++) {
        int col  = gx * 128 + wn * 64 + ni * 16 + l15;
        float bj = bias[col];
#pragma unroll
        for (int mi = 0; mi < 4; mi++)
#pragma unroll
            for (int r = 0; r < 4; r++) {
                int row = gy * 128 + wm * 64 + mi * 16 + quad * 4 + r;  // 0..8191
                out[(size_t)row * 768 + col] = acc[mi][ni][r] + bj;
            }
    }
}

// ---------------------------------------------------------------------------
// Dual-stream flash attention (unchanged): 2 waves/block, wave owns 32 q-rows
// as TWO register-resident q-sets -> every K/V LDS fragment feeds 2 MFMAs.
// 32-key tiles, 32 iters, double-buffered; wave0 stages K, wave1 stages V.
// Grid 768 (16 qt x 48 bh), LDS 41 KB -> 3 blocks/CU. (LDS reads already
// lane-linear = conflict-free.)
// ---------------------------------------------------------------------------
__global__ __launch_bounds__(128, 2)
void attn_k(const __bf16* __restrict__ qws, const __bf16* __restrict__ kws,
            const __bf16* __restrict__ vws, __bf16* __restrict__ ows)
{
    __shared__ __bf16 Ks[2][2][2][2][512];  // [buf][s][kk][mi2][lane*8] 16 KB
    __shared__ __bf16 Vs[2][2][4][512];     // [buf][s][mi4][lane*8]     16 KB
    __shared__ __bf16 Ps[2][2][16 * 72];    // [wave][set][row*72]        9 KB

    const int g  = blockIdx.x;
    const int qt = g / 48;              // 0..15
    const int bh = g % 48;              // 0..47
    const int b = bh / 12, h = bh % 12;
    const int t = threadIdx.x, w = t >> 6, lane = t & 63;
    const int l15 = lane & 15, quad = lane >> 4;

    const size_t head_off = (size_t)bh * 65536;          // 1024*64
    const size_t ss       = (size_t)48 * 65536;          // stream stride

    // Q: 2 sets x 2 streams x 2 kk -> 8 bf16x8 (32 VGPR), register-resident
    bf16x8 qf[2][2][2];
#pragma unroll
    for (int set = 0; set < 2; set++)
#pragma unroll
        for (int s = 0; s < 2; s++)
#pragma unroll
            for (int kk = 0; kk < 2; kk++)
                qf[set][s][kk] = *(const bf16x8*)(qws + s * ss + head_off
                    + (size_t)(qt * 64 + w * 32 + set * 16 + l15) * 64 + kk * 32 + quad * 8);

    float lsum[2] = {0.f, 0.f};         // per-lane partial sums, q = l15 per set
    f32x4 accO[2][2][4];                // [set][s][mi]: col(l15)=q, row=d-part
#pragma unroll
    for (int set = 0; set < 2; set++)
#pragma unroll
        for (int s = 0; s < 2; s++)
#pragma unroll
            for (int mi = 0; mi < 4; mi++) accO[set][s][mi] = f32x4{0.f, 0.f, 0.f, 0.f};

    const __bf16* kbase = kws + head_off;
    const __bf16* vbase = vws + head_off;

    // ---- staging helper (wave-uniform role: w==0 -> K, w==1 -> V)
    // K frag: 16 keys x 32 d-elems; V frag: 16 d-rows x 32 keys (V^T layout)
#define STAGE_TILE(BUF, KEYB)                                                   \
    do {                                                                        \
        if (w == 0) {                                                           \
            _Pragma("unroll")                                                   \
            for (int i = 0; i < 8; i++) {                                       \
                const int s = i >> 2, kk = (i >> 1) & 1, mi = i & 1;            \
                async16(kbase + s * ss + (size_t)((KEYB) + mi * 16 + l15) * 64  \
                            + kk * 32 + quad * 8,                               \
                        &Ks[BUF][s][kk][mi][lane * 8]);                         \
            }                                                                   \
        } else {                                                                \
            _Pragma("unroll")                                                   \
            for (int i = 0; i < 8; i++) {                                       \
                const int s = i >> 2, mi = i & 3;                               \
                async16(vbase + s * ss + (size_t)(mi * 16 + l15) * 1024         \
                            + (KEYB) + quad * 8,                                \
                        &Vs[BUF][s][mi][lane * 8]);                             \
            }                                                                   \
        }                                                                       \
    } while (0)

    // prologue: stage tile 0 into buf 0
    STAGE_TILE(0, 0);
    __syncthreads();

#pragma unroll 2
    for (int kt = 0; kt < 32; kt++) {
        const int cb = kt & 1, nb = cb ^ 1;

        // 1-deep prefetch of next 32-key tile (overlaps with compute below)
        if (kt < 31) STAGE_TILE(nb, (kt + 1) * 32);

        // ---- QK^T: accS[set][mi], S = S1+S2 in one accumulation chain.
        // Each kf read feeds BOTH q-sets.
        f32x4 accS[2][2];
#pragma unroll
        for (int set = 0; set < 2; set++)
#pragma unroll
            for (int mi = 0; mi < 2; mi++) accS[set][mi] = f32x4{0.f, 0.f, 0.f, 0.f};
        __builtin_amdgcn_s_setprio(1);
#pragma unroll
        for (int s = 0; s < 2; s++)
#pragma unroll
            for (int kk = 0; kk < 2; kk++) {
                bf16x8 kf0 = *(const bf16x8*)&Ks[cb][s][kk][0][lane * 8];
                bf16x8 kf1 = *(const bf16x8*)&Ks[cb][s][kk][1][lane * 8];
#pragma unroll
                for (int set = 0; set < 2; set++) {
                    accS[set][0] = __builtin_amdgcn_mfma_f32_16x16x32_bf16(kf0, qf[set][s][kk], accS[set][0], 0, 0, 0);
                    accS[set][1] = __builtin_amdgcn_mfma_f32_16x16x32_bf16(kf1, qf[set][s][kk], accS[set][1], 0, 0, 0);
                }
            }
        __builtin_amdgcn_s_setprio(0);

        // ---- softmax numerator (no-max; scores bounded), per-lane l
#pragma unroll
        for (int set = 0; set < 2; set++) {
            float rs = 0.f;
#pragma unroll
            for (int mi = 0; mi < 2; mi++) {
                bf16x4 pk;
#pragma unroll
                for (int r = 0; r < 4; r++) {
                    float pv = __expf(accS[set][mi][r]);
                    pk[r] = (__bf16)pv;
                    rs += pv;
                }
                *(bf16x4*)&Ps[w][set][l15 * 72 + mi * 16 + quad * 4] = pk;
            }
            lsum[set] += rs;
        }

        // ---- PV (O^T = V^T @ P^T). Each vf read feeds BOTH q-sets.
        bf16x8 pa0 = *(const bf16x8*)&Ps[w][0][l15 * 72 + quad * 8];
        bf16x8 pa1 = *(const bf16x8*)&Ps[w][1][l15 * 72 + quad * 8];
        __builtin_amdgcn_s_setprio(1);
#pragma unroll
        for (int s = 0; s < 2; s++)
#pragma unroll
            for (int mi = 0; mi < 4; mi++) {
                bf16x8 vf = *(const bf16x8*)&Vs[cb][s][mi][lane * 8];
                accO[0][s][mi] = __builtin_amdgcn_mfma_f32_16x16x32_bf16(vf, pa0, accO[0][s][mi], 0, 0, 0);
                accO[1][s][mi] = __builtin_amdgcn_mfma_f32_16x16x32_bf16(vf, pa1, accO[1][s][mi], 0, 0, 0);
            }
        __builtin_amdgcn_s_setprio(0);

        // one barrier per iteration: prefetch (issued at iter start) has the
        // whole compute phase to land; also protects WAR on buffer swap.
        __syncthreads();
    }
#undef STAGE_TILE

#pragma unroll
    for (int set = 0; set < 2; set++) {
        float l = lsum[set];
        l += __shfl_xor(l, 16);
        l += __shfl_xor(l, 32);
        float il = 1.f / l;             // per-lane, q = l15

        const int tok = qt * 64 + w * 32 + set * 16 + l15;
#pragma unroll
        for (int s = 0; s < 2; s++)
#pragma unroll
            for (int mi = 0; mi < 4; mi++) {
                bf16x4 ov;
#pragma unroll
                for (int r = 0; r < 4; r++) ov[r] = (__bf16)(accO[set][s][mi][r] * il);
                *(bf16x4*)&ows[((size_t)((s * 4 + b) * 1024 + tok)) * 768
                               + h * 64 + mi * 16 + quad * 4] = ov;
            }
    }
}

// ---------------------------------------------------------------------------
extern "C" void kernel_launch(void* const* d_in, const int* in_sizes, int n_in,
                              void* d_out, int out_size, void* d_ws, size_t ws_size,
                              hipStream_t stream)
{
    const float* x1    = (const float*)d_in[0];
    const float* x2    = (const float*)d_in[1];
    const float* Wqkv  = (const float*)d_in[2];
    const float* bqkv  = (const float*)d_in[3];
    const float* Wproj = (const float*)d_in[4];
    const float* bproj = (const float*)d_in[5];
    float* out = (float*)d_out;

    // ws: q | k | v | pool (4 x 6291456 bf16 = 50.33 MB proven footprint),
    // plus OPTIONAL Wpc zone at +50.33 MB if ws_size allows (saves a launch).
    // x1c/x2c live in d_out (dead before proj writes it).
    const size_t qkv_elems = (size_t)2 * 4 * 12 * 1024 * 64;   // 6,291,456
    __bf16* q_ws = (__bf16*)d_ws;
    __bf16* k_ws = q_ws + qkv_elems;
    __bf16* v_ws = k_ws + qkv_elems;
    __bf16* pool = v_ws + qkv_elems;
    __bf16* Wqc  = pool + 3145728;      // 2304*768 (dead after QKV GEMMs)
    __bf16* o_ws = pool;                // 8192*768 (attn out; overwrites Wqc zone)
    __bf16* Xc   = (__bf16*)d_out;      // x1c | x2c (scratch use of out buffer)

    const bool big = ws_size >= (size_t)(4 * qkv_elems + 589824) * sizeof(__bf16);
    __bf16* Wpc = big ? (pool + qkv_elems)   // past proven footprint, untouched by attn
                      : q_ws;                // legacy: q dead after attn

    // 1) fused fp32->bf16 converts (Wproj folded in when ws allows)
    cvt4_k<<<big ? 4224 : 3936, 256, 0, stream>>>(x1, x2, Wqkv, Wproj, Xc, Wqc, Wpc);
    // 2) QKV GEMM, both streams, XCD-ownership swizzle, 3-buf + k-major LDS
    gemm_qkv_s<<<1152, 256, 0, stream>>>(Xc, Wqc, bqkv, q_ws, k_ws, v_ws);
    // 3) attention (32-key tiles, 2 q-sets/wave, 2 waves/block, 3 blocks/CU)
    attn_k<<<768, 128, 0, stream>>>(q_ws, k_ws, v_ws, o_ws);
    // 4) legacy proj weight convert only if ws too small for the fused path
    if (!big) cvt_k<<<288, 256, 0, stream>>>(Wproj, Wpc, 589824);
    // 5) proj GEMM -> d_out fp32 (y1 ‖ y2), 3-buf + k-major LDS
    gemm_proj<<<dim3(6, 64), 256, 0, stream>>>(o_ws, Wpc, bproj, out);
}

// Round 8
// 208.345 us; speedup vs baseline: 1.1422x; 1.1422x over previous
//
#include <hip/hip_runtime.h>
#include <hip/hip_bf16.h>

// B=4, N=1024, C=768, H=12, D=64, SCALE=1/8. Inputs fp32, output fp32.
// Internal math bf16 MFMA. fp32->bf16 pre-convert enables global_load_lds(16B).
//
// GLOBAL K-MAJOR TILED LAYOUT for all GEMM operands (Xc, Wqc, Wpc, o_ws):
//   [G][kt][kslot][r][ke]  where G = row/16, r = row%16, kt = k/32,
//   kslot = (k%32)/8, ke = k%8.  One (G,kt) block = 512 elems = 1 KB.
// Staging then reads a CONTIGUOUS 1 KB per global_load_lds (base + lane*16B),
// LDS stays linear, and MFMA fragment reads are group_base + lane*16B ->
// sequential 1 KB stream, ZERO bank conflicts. (Round-6 lesson: permuting the
// source of a row-major layout breaks lane-contiguity; so permute the LAYOUT.)

typedef __bf16 bf16x8 __attribute__((ext_vector_type(8)));
typedef __bf16 bf16x4 __attribute__((ext_vector_type(4)));
typedef float  f32x4  __attribute__((ext_vector_type(4)));

__device__ __forceinline__ bf16x8 cvt8(const float* p) {
    f32x4 f0 = *(const f32x4*)p;
    f32x4 f1 = *(const f32x4*)(p + 4);
    bf16x8 r;
    r[0] = (__bf16)f0[0]; r[1] = (__bf16)f0[1]; r[2] = (__bf16)f0[2]; r[3] = (__bf16)f0[3];
    r[4] = (__bf16)f1[0]; r[5] = (__bf16)f1[1]; r[6] = (__bf16)f1[2]; r[7] = (__bf16)f1[3];
    return r;
}

__device__ __forceinline__ void async16(const __bf16* g, __bf16* l) {
    __builtin_amdgcn_global_load_lds(
        (const __attribute__((address_space(1))) void*)g,
        (__attribute__((address_space(3))) void*)l, 16, 0, 0);
}

// ---------------------------------------------------------------------------
// Fused convert to TILED layout, dst-linear: thread j owns tiled 8-elem run
// j*8 (writes fully contiguous 16B); src read = tok*768 + c (each 128B line
// consumed by 4 lanes). Decode: r=j&15, ks=(j>>4)&3, t2=j>>6, kt=t2%24,
// G=t2/24, tok=G*16+r, c=kt*32+ks*8.
// ---------------------------------------------------------------------------
__device__ __forceinline__ void cvt_tiled_one(const float* __restrict__ src,
                                              __bf16* __restrict__ dst, int j) {
    const int r  = j & 15;
    const int ks = (j >> 4) & 3;
    const int t2 = j >> 6;
    const int kt = t2 % 24;
    const int G  = t2 / 24;
    *(bf16x8*)(dst + (size_t)j * 8) =
        cvt8(src + (size_t)(G * 16 + r) * 768 + kt * 32 + ks * 8);
}

__global__ __launch_bounds__(256)
void cvt4_k(const float* __restrict__ x1, const float* __restrict__ x2,
            const float* __restrict__ wq, const float* __restrict__ wp,
            __bf16* __restrict__ xc, __bf16* __restrict__ wqc,
            __bf16* __restrict__ wpc)
{
    int bid = blockIdx.x;
    if (bid < 1536)      cvt_tiled_one(x1, xc,            bid * 256 + threadIdx.x);
    else if (bid < 3072) cvt_tiled_one(x2, xc + 3145728, (bid - 1536) * 256 + threadIdx.x);
    else if (bid < 3936) cvt_tiled_one(wq, wqc,          (bid - 3072) * 256 + threadIdx.x);
    else                 cvt_tiled_one(wp, wpc,          (bid - 3936) * 256 + threadIdx.x);
}

__global__ __launch_bounds__(256)
void cvt_kt(const float* __restrict__ src, __bf16* __restrict__ dst, int nrun) {
    int j = blockIdx.x * 256 + threadIdx.x;
    if (j < nrun) cvt_tiled_one(src, dst, j);
}

// ---------------------------------------------------------------------------
// QKV GEMM, 128x128 tile, BK=32, 3-buffer counted-vmcnt pipeline (round-3
// structure, measured best) on TILED operands: each wave stages its 2 A-groups
// + 2 B-groups as four contiguous-1KB global_load_lds; fragment reads are
// group_base + lane*16B (0 conflicts). vmcnt(4): tile kt landed, kt+1 in
// flight across the barrier. Race: writer at kt targets buf[(kt+1)%3];
// slowest reader uses buf[(kt-1)%3] - disjoint. XCD-ownership swizzle kept.
// ---------------------------------------------------------------------------
__global__ __launch_bounds__(256)
void gemm_qkv_s(const __bf16* __restrict__ Xc, const __bf16* __restrict__ Wq,
                const float* __restrict__ bias,
                __bf16* __restrict__ qo, __bf16* __restrict__ ko,
                __bf16* __restrict__ vo)
{
    __shared__ __bf16 As[3][128 * 32];   // 24 KB (8 groups x 512 elems)
    __shared__ __bf16 Bs[3][128 * 32];   // 24 KB

    const int t = threadIdx.x, w = t >> 6, lane = t & 63;
    const int l15 = lane & 15, quad = lane >> 4;
    const int wm = w >> 1, wn = w & 1;

    // XCD-ownership decode: bid%8 = XCD; (gy,st) constant per (xcd,pair)
    const int bid  = blockIdx.x;          // 0..1151
    const int xcd  = bid & 7;
    const int i6   = bid >> 3;            // 0..143
    const int pair = i6 / 18;             // 0..7
    const int gx   = i6 - pair * 18;      // 0..17
    const int p    = xcd * 8 + pair;      // 0..63
    const int gy   = p & 31;
    const int st   = p >> 5;

    // tiled bases: tile row-group range [gy*8, gy*8+8) / [gx*8, gx*8+8)
    const __bf16* Ab = Xc + (size_t)st * 3145728 + (size_t)(gy * 8) * 24 * 512;
    const __bf16* Bb = Wq + (size_t)(gx * 8) * 24 * 512;

    f32x4 acc[4][4];
#pragma unroll
    for (int mi = 0; mi < 4; mi++)
#pragma unroll
        for (int ni = 0; ni < 4; ni++) acc[mi][ni] = f32x4{0.f, 0.f, 0.f, 0.f};

    const int ga0 = w * 2, ga1 = w * 2 + 1;     // this wave's groups

#define QSTAGE(BUF, KT)                                                          \
    do {                                                                         \
        async16(Ab + ((size_t)ga0 * 24 + (KT)) * 512 + lane * 8,                 \
                &As[BUF][ga0 * 512 + lane * 8]);                                 \
        async16(Ab + ((size_t)ga1 * 24 + (KT)) * 512 + lane * 8,                 \
                &As[BUF][ga1 * 512 + lane * 8]);                                 \
        async16(Bb + ((size_t)ga0 * 24 + (KT)) * 512 + lane * 8,                 \
                &Bs[BUF][ga0 * 512 + lane * 8]);                                 \
        async16(Bb + ((size_t)ga1 * 24 + (KT)) * 512 + lane * 8,                 \
                &Bs[BUF][ga1 * 512 + lane * 8]);                                 \
    } while (0)

    // prologue: stage K-step 0 into buf 0
    QSTAGE(0, 0);

#pragma unroll 3
    for (int kt = 0; kt < 24; kt++) {
        const int cb = kt % 3;
        if (kt < 23) {
            QSTAGE((kt + 1) % 3, kt + 1);
            asm volatile("s_waitcnt vmcnt(4)" ::: "memory");  // kt landed; kt+1 in flight
        } else {
            asm volatile("s_waitcnt vmcnt(0)" ::: "memory");  // tail drain
        }
        __builtin_amdgcn_s_barrier();
        __builtin_amdgcn_sched_barrier(0);

        bf16x8 af[4], bfr[4];
#pragma unroll
        for (int mi = 0; mi < 4; mi++)
            af[mi] = *(const bf16x8*)&As[cb][(wm * 4 + mi) * 512 + lane * 8];
#pragma unroll
        for (int ni = 0; ni < 4; ni++)
            bfr[ni] = *(const bf16x8*)&Bs[cb][(wn * 4 + ni) * 512 + lane * 8];
#pragma unroll
        for (int mi = 0; mi < 4; mi++)
#pragma unroll
            for (int ni = 0; ni < 4; ni++)
                acc[mi][ni] = __builtin_amdgcn_mfma_f32_16x16x32_bf16(af[mi], bfr[ni], acc[mi][ni], 0, 0, 0);
    }
#undef QSTAGE

    const int which = (gx * 128) / 768;   // uniform per block (tile never spans)

    if (which == 2) {
        // V: packed bf16x4 stores, 4 consecutive tokens (aligned, b-safe)
#pragma unroll
        for (int ni = 0; ni < 4; ni++) {
            int j = gx * 128 + wn * 64 + ni * 16 + l15;
            int c = j - 1536;
            int h = c >> 6, d = c & 63;
            float bj = bias[j];
#pragma unroll
            for (int mi = 0; mi < 4; mi++) {
                int row0 = gy * 128 + wm * 64 + mi * 16 + quad * 4;
                int b = row0 >> 10, tok0 = row0 & 1023;
                bf16x4 pv;
#pragma unroll
                for (int r = 0; r < 4; r++) pv[r] = (__bf16)(acc[mi][ni][r] + bj);
                *(bf16x4*)&vo[((size_t)((st * 4 + b) * 12 + h) * 64 + d) * 1024 + tok0] = pv;
            }
        }
    } else {
        // Q / K: lane-coalesced scalar stores (d consecutive across l15)
#pragma unroll
        for (int ni = 0; ni < 4; ni++) {
            int j     = gx * 128 + wn * 64 + ni * 16 + l15;   // 0..1535
            int c     = j - which * 768;
            int h = c >> 6, d = c & 63;
            float bj  = bias[j];
#pragma unroll
            for (int mi = 0; mi < 4; mi++) {
#pragma unroll
                for (int r = 0; r < 4; r++) {
                    int row = gy * 128 + wm * 64 + mi * 16 + quad * 4 + r;
                    int b = row >> 10, tok = row & 1023;
                    float val = acc[mi][ni][r] + bj;
                    if (which == 0)
                        qo[((size_t)((st * 4 + b) * 12 + h) * 1024 + tok) * 64 + d] = (__bf16)(val * 0.125f);
                    else
                        ko[((size_t)((st * 4 + b) * 12 + h) * 1024 + tok) * 64 + d] = (__bf16)val;
                }
            }
        }
    }
}

// ---------------------------------------------------------------------------
// 128x128-tile proj GEMM, BK=32, same 3-buffer pipeline on TILED operands.
// A = o_ws tiled [512 groups][24][512]; W = Wpc tiled [48 groups][24][512].
// ---------------------------------------------------------------------------
__global__ __launch_bounds__(256)
void gemm_proj(const __bf16* __restrict__ A, const __bf16* __restrict__ Wp,
               const float* __restrict__ bias, float* __restrict__ out)
{
    __shared__ __bf16 As[3][128 * 32];
    __shared__ __bf16 Bs[3][128 * 32];

    const int t = threadIdx.x, w = t >> 6, lane = t & 63;
    const int l15 = lane & 15, quad = lane >> 4;
    const int wm = w >> 1, wn = w & 1;
    const int gx = blockIdx.x, gy = blockIdx.y;

    const __bf16* Ab = A  + (size_t)(gy * 8) * 24 * 512;
    const __bf16* Bb = Wp + (size_t)(gx * 8) * 24 * 512;

    f32x4 acc[4][4];
#pragma unroll
    for (int mi = 0; mi < 4; mi++)
#pragma unroll
        for (int ni = 0; ni < 4; ni++) acc[mi][ni] = f32x4{0.f, 0.f, 0.f, 0.f};

    const int ga0 = w * 2, ga1 = w * 2 + 1;

#define PSTAGE(BUF, KT)                                                          \
    do {                                                                         \
        async16(Ab + ((size_t)ga0 * 24 + (KT)) * 512 + lane * 8,                 \
                &As[BUF][ga0 * 512 + lane * 8]);                                 \
        async16(Ab + ((size_t)ga1 * 24 + (KT)) * 512 + lane * 8,                 \
                &As[BUF][ga1 * 512 + lane * 8]);                                 \
        async16(Bb + ((size_t)ga0 * 24 + (KT)) * 512 + lane * 8,                 \
                &Bs[BUF][ga0 * 512 + lane * 8]);                                 \
        async16(Bb + ((size_t)ga1 * 24 + (KT)) * 512 + lane * 8,                 \
                &Bs[BUF][ga1 * 512 + lane * 8]);                                 \
    } while (0)

    PSTAGE(0, 0);

#pragma unroll 3
    for (int kt = 0; kt < 24; kt++) {
        const int cb = kt % 3;
        if (kt < 23) {
            PSTAGE((kt + 1) % 3, kt + 1);
            asm volatile("s_waitcnt vmcnt(4)" ::: "memory");
        } else {
            asm volatile("s_waitcnt vmcnt(0)" ::: "memory");
        }
        __builtin_amdgcn_s_barrier();
        __builtin_amdgcn_sched_barrier(0);

        bf16x8 af[4], bfr[4];
#pragma unroll
        for (int mi = 0; mi < 4; mi++)
            af[mi] = *(const bf16x8*)&As[cb][(wm * 4 + mi) * 512 + lane * 8];
#pragma unroll
        for (int ni = 0; ni < 4; ni++)
            bfr[ni] = *(const bf16x8*)&Bs[cb][(wn * 4 + ni) * 512 + lane * 8];
#pragma unroll
        for (int mi = 0; mi < 4; mi++)
#pragma unroll
            for (int ni = 0; ni < 4; ni++)
                acc[mi][ni] = __builtin_amdgcn_mfma_f32_16x16x32_bf16(af[mi], bfr[ni], acc[mi][ni], 0, 0, 0);
    }
#undef PSTAGE

#pragma unroll
    for (int ni = 0; ni < 4; ni++) {
        int col  = gx * 128 + wn * 64 + ni * 16 + l15;
        float bj = bias[col];
#pragma unroll
        for (int mi = 0; mi < 4; mi++)
#pragma unroll
            for (int r = 0; r < 4; r++) {
                int row = gy * 128 + wm * 64 + mi * 16 + quad * 4 + r;  // 0..8191
                out[(size_t)row * 768 + col] = acc[mi][ni][r] + bj;
            }
    }
}

// ---------------------------------------------------------------------------
// Dual-stream flash attention (structure unchanged): 2 waves/block, 2 q-sets/
// wave, 32-key tiles, double-buffered; wave0 stages K, wave1 stages V.
// Grid 768, LDS 41 KB -> 3 blocks/CU. EPILOGUE now writes o_ws in the TILED
// layout (consumed by gemm_proj's contiguous staging).
// ---------------------------------------------------------------------------
__global__ __launch_bounds__(128, 2)
void attn_k(const __bf16* __restrict__ qws, const __bf16* __restrict__ kws,
            const __bf16* __restrict__ vws, __bf16* __restrict__ ows)
{
    __shared__ __bf16 Ks[2][2][2][2][512];  // [buf][s][kk][mi2][lane*8] 16 KB
    __shared__ __bf16 Vs[2][2][4][512];     // [buf][s][mi4][lane*8]     16 KB
    __shared__ __bf16 Ps[2][2][16 * 72];    // [wave][set][row*72]        9 KB

    const int g  = blockIdx.x;
    const int qt = g / 48;              // 0..15
    const int bh = g % 48;              // 0..47
    const int b = bh / 12, h = bh % 12;
    const int t = threadIdx.x, w = t >> 6, lane = t & 63;
    const int l15 = lane & 15, quad = lane >> 4;

    const size_t head_off = (size_t)bh * 65536;          // 1024*64
    const size_t ss       = (size_t)48 * 65536;          // stream stride

    // Q: 2 sets x 2 streams x 2 kk -> 8 bf16x8 (32 VGPR), register-resident
    bf16x8 qf[2][2][2];
#pragma unroll
    for (int set = 0; set < 2; set++)
#pragma unroll
        for (int s = 0; s < 2; s++)
#pragma unroll
            for (int kk = 0; kk < 2; kk++)
                qf[set][s][kk] = *(const bf16x8*)(qws + s * ss + head_off
                    + (size_t)(qt * 64 + w * 32 + set * 16 + l15) * 64 + kk * 32 + quad * 8);

    float lsum[2] = {0.f, 0.f};         // per-lane partial sums, q = l15 per set
    f32x4 accO[2][2][4];                // [set][s][mi]: col(l15)=q, row=d-part
#pragma unroll
    for (int set = 0; set < 2; set++)
#pragma unroll
        for (int s = 0; s < 2; s++)
#pragma unroll
            for (int mi = 0; mi < 4; mi++) accO[set][s][mi] = f32x4{0.f, 0.f, 0.f, 0.f};

    const __bf16* kbase = kws + head_off;
    const __bf16* vbase = vws + head_off;

    // ---- staging helper (wave-uniform role: w==0 -> K, w==1 -> V)
#define STAGE_TILE(BUF, KEYB)                                                   \
    do {                                                                        \
        if (w == 0) {                                                           \
            _Pragma("unroll")                                                   \
            for (int i = 0; i < 8; i++) {                                       \
                const int s = i >> 2, kk = (i >> 1) & 1, mi = i & 1;            \
                async16(kbase + s * ss + (size_t)((KEYB) + mi * 16 + l15) * 64  \
                            + kk * 32 + quad * 8,                               \
                        &Ks[BUF][s][kk][mi][lane * 8]);                         \
            }                                                                   \
        } else {                                                                \
            _Pragma("unroll")                                                   \
            for (int i = 0; i < 8; i++) {                                       \
                const int s = i >> 2, mi = i & 3;                               \
                async16(vbase + s * ss + (size_t)(mi * 16 + l15) * 1024         \
                            + (KEYB) + quad * 8,                                \
                        &Vs[BUF][s][mi][lane * 8]);                             \
            }                                                                   \
        }                                                                       \
    } while (0)

    // prologue: stage tile 0 into buf 0
    STAGE_TILE(0, 0);
    __syncthreads();

#pragma unroll 2
    for (int kt = 0; kt < 32; kt++) {
        const int cb = kt & 1, nb = cb ^ 1;

        // 1-deep prefetch of next 32-key tile (overlaps with compute below)
        if (kt < 31) STAGE_TILE(nb, (kt + 1) * 32);

        // ---- QK^T: accS[set][mi], S = S1+S2 in one accumulation chain.
        f32x4 accS[2][2];
#pragma unroll
        for (int set = 0; set < 2; set++)
#pragma unroll
            for (int mi = 0; mi < 2; mi++) accS[set][mi] = f32x4{0.f, 0.f, 0.f, 0.f};
        __builtin_amdgcn_s_setprio(1);
#pragma unroll
        for (int s = 0; s < 2; s++)
#pragma unroll
            for (int kk = 0; kk < 2; kk++) {
                bf16x8 kf0 = *(const bf16x8*)&Ks[cb][s][kk][0][lane * 8];
                bf16x8 kf1 = *(const bf16x8*)&Ks[cb][s][kk][1][lane * 8];
#pragma unroll
                for (int set = 0; set < 2; set++) {
                    accS[set][0] = __builtin_amdgcn_mfma_f32_16x16x32_bf16(kf0, qf[set][s][kk], accS[set][0], 0, 0, 0);
                    accS[set][1] = __builtin_amdgcn_mfma_f32_16x16x32_bf16(kf1, qf[set][s][kk], accS[set][1], 0, 0, 0);
                }
            }
        __builtin_amdgcn_s_setprio(0);

        // ---- softmax numerator (no-max; scores bounded), per-lane l
#pragma unroll
        for (int set = 0; set < 2; set++) {
            float rs = 0.f;
#pragma unroll
            for (int mi = 0; mi < 2; mi++) {
                bf16x4 pk;
#pragma unroll
                for (int r = 0; r < 4; r++) {
                    float pv = __expf(accS[set][mi][r]);
                    pk[r] = (__bf16)pv;
                    rs += pv;
                }
                *(bf16x4*)&Ps[w][set][l15 * 72 + mi * 16 + quad * 4] = pk;
            }
            lsum[set] += rs;
        }

        // ---- PV (O^T = V^T @ P^T). Each vf read feeds BOTH q-sets.
        bf16x8 pa0 = *(const bf16x8*)&Ps[w][0][l15 * 72 + quad * 8];
        bf16x8 pa1 = *(const bf16x8*)&Ps[w][1][l15 * 72 + quad * 8];
        __builtin_amdgcn_s_setprio(1);
#pragma unroll
        for (int s = 0; s < 2; s++)
#pragma unroll
            for (int mi = 0; mi < 4; mi++) {
                bf16x8 vf = *(const bf16x8*)&Vs[cb][s][mi][lane * 8];
                accO[0][s][mi] = __builtin_amdgcn_mfma_f32_16x16x32_bf16(vf, pa0, accO[0][s][mi], 0, 0, 0);
                accO[1][s][mi] = __builtin_amdgcn_mfma_f32_16x16x32_bf16(vf, pa1, accO[1][s][mi], 0, 0, 0);
            }
        __builtin_amdgcn_s_setprio(0);

        __syncthreads();
    }
#undef STAGE_TILE

#pragma unroll
    for (int set = 0; set < 2; set++) {
        float l = lsum[set];
        l += __shfl_xor(l, 16);
        l += __shfl_xor(l, 32);
        float il = 1.f / l;             // per-lane, q = l15

        const int tok = qt * 64 + w * 32 + set * 16 + l15;
#pragma unroll
        for (int s = 0; s < 2; s++)
#pragma unroll
            for (int mi = 0; mi < 4; mi++) {
                bf16x4 ov;
#pragma unroll
                for (int r = 0; r < 4; r++) ov[r] = (__bf16)(accO[set][s][mi][r] * il);
                // TILED o_ws store: row=(s*4+b)*1024+tok, c=h*64+mi*16+quad*4
                const int row = (s * 4 + b) * 1024 + tok;
                const int c   = h * 64 + mi * 16 + quad * 4;
                const size_t off = ((size_t)(row >> 4) * 24 + (c >> 5)) * 512
                                 + ((c >> 3) & 3) * 128 + (row & 15) * 8 + (c & 7);
                *(bf16x4*)&ows[off] = ov;
            }
    }
}

// ---------------------------------------------------------------------------
extern "C" void kernel_launch(void* const* d_in, const int* in_sizes, int n_in,
                              void* d_out, int out_size, void* d_ws, size_t ws_size,
                              hipStream_t stream)
{
    const float* x1    = (const float*)d_in[0];
    const float* x2    = (const float*)d_in[1];
    const float* Wqkv  = (const float*)d_in[2];
    const float* bqkv  = (const float*)d_in[3];
    const float* Wproj = (const float*)d_in[4];
    const float* bproj = (const float*)d_in[5];
    float* out = (float*)d_out;

    // ws: q | k | v | pool (4 x 6291456 bf16 = 50.33 MB proven footprint),
    // plus OPTIONAL Wpc zone at +50.33 MB if ws_size allows (saves a launch).
    // x1c/x2c live in d_out (dead before proj writes it). All GEMM operand
    // buffers are in the TILED layout.
    const size_t qkv_elems = (size_t)2 * 4 * 12 * 1024 * 64;   // 6,291,456
    __bf16* q_ws = (__bf16*)d_ws;
    __bf16* k_ws = q_ws + qkv_elems;
    __bf16* v_ws = k_ws + qkv_elems;
    __bf16* pool = v_ws + qkv_elems;
    __bf16* Wqc  = pool + 3145728;      // 2304*768 (dead after QKV GEMMs)
    __bf16* o_ws = pool;                // 8192*768 tiled (attn out)
    __bf16* Xc   = (__bf16*)d_out;      // x1c | x2c tiled (scratch in out buf)

    const bool big = ws_size >= (size_t)(4 * qkv_elems + 589824) * sizeof(__bf16);
    __bf16* Wpc = big ? (pool + qkv_elems)   // past proven footprint
                      : q_ws;                // legacy: q dead after attn

    // 1) fused fp32->bf16 tiled converts (Wproj folded in when ws allows)
    cvt4_k<<<big ? 4224 : 3936, 256, 0, stream>>>(x1, x2, Wqkv, Wproj, Xc, Wqc, Wpc);
    // 2) QKV GEMM, tiled operands, XCD-ownership swizzle, 3-buf counted-vmcnt
    gemm_qkv_s<<<1152, 256, 0, stream>>>(Xc, Wqc, bqkv, q_ws, k_ws, v_ws);
    // 3) attention (tiled o_ws epilogue)
    attn_k<<<768, 128, 0, stream>>>(q_ws, k_ws, v_ws, o_ws);
    // 4) legacy tiled proj weight convert only if ws too small
    if (!big) cvt_kt<<<288, 256, 0, stream>>>(Wproj, Wpc, 73728);
    // 5) proj GEMM -> d_out fp32 (y1 ‖ y2), tiled operands
    gemm_proj<<<dim3(6, 64), 256, 0, stream>>>(o_ws, Wpc, bproj, out);
}

// Round 9
// 206.934 us; speedup vs baseline: 1.1500x; 1.0068x over previous
//
#include <hip/hip_runtime.h>
#include <hip/hip_bf16.h>

// B=4, N=1024, C=768, H=12, D=64, SCALE=1/8. Inputs fp32, output fp32.
// Internal math bf16 MFMA. fp32->bf16 pre-convert enables global_load_lds(16B).
//
// GLOBAL K-MAJOR TILED LAYOUT for all GEMM operands (Xc, Wqc, Wpc, o_ws):
//   [G][kt][kslot][r][ke]  where G = row/16, r = row%16, kt = k/32,
//   kslot = (k%32)/8, ke = k%8.  One (G,kt) block = 512 elems = 1 KB.
// Staging reads a CONTIGUOUS 1 KB per global_load_lds (base + lane*16B),
// LDS stays linear, MFMA fragment reads are group_base + lane*16B ->
// sequential 1 KB stream, ZERO bank conflicts (verified round 7).

typedef __bf16 bf16x8 __attribute__((ext_vector_type(8)));
typedef __bf16 bf16x4 __attribute__((ext_vector_type(4)));
typedef float  f32x4  __attribute__((ext_vector_type(4)));

__device__ __forceinline__ bf16x8 cvt8(const float* p) {
    f32x4 f0 = *(const f32x4*)p;
    f32x4 f1 = *(const f32x4*)(p + 4);
    bf16x8 r;
    r[0] = (__bf16)f0[0]; r[1] = (__bf16)f0[1]; r[2] = (__bf16)f0[2]; r[3] = (__bf16)f0[3];
    r[4] = (__bf16)f1[0]; r[5] = (__bf16)f1[1]; r[6] = (__bf16)f1[2]; r[7] = (__bf16)f1[3];
    return r;
}

__device__ __forceinline__ void async16(const __bf16* g, __bf16* l) {
    __builtin_amdgcn_global_load_lds(
        (const __attribute__((address_space(1))) void*)g,
        (__attribute__((address_space(3))) void*)l, 16, 0, 0);
}

// ---------------------------------------------------------------------------
// Tiled convert via LDS transpose: one block per 16-row group (G).
// Phase 1: coalesced f32x8 row-major reads -> bf16 -> LDS (padded rows).
// Phase 2: tiled-permutation reads from LDS -> G-stripe written FULLY
// CONTIGUOUS (wave = 1 KB). Both global sides perfectly coalesced (round-7's
// dst-linear/src-scattered cvt was the anti-pattern: 32B reads at 3KB stride).
// Grid: x1 G0..255 | x2 G256..511 | Wq G512..655 | [Wp G656..703 if big].
// ---------------------------------------------------------------------------
__global__ __launch_bounds__(256)
void cvt4_k(const float* __restrict__ x1, const float* __restrict__ x2,
            const float* __restrict__ wq, const float* __restrict__ wp,
            __bf16* __restrict__ xc, __bf16* __restrict__ wqc,
            __bf16* __restrict__ wpc)
{
    __shared__ __bf16 L[16][776];        // +8 pad
    const int bid = blockIdx.x, t = threadIdx.x;
    const float* src; __bf16* dst; int G;
    if (bid < 256)      { src = x1; dst = xc;            G = bid; }
    else if (bid < 512) { src = x2; dst = xc + 3145728;  G = bid - 256; }
    else if (bid < 656) { src = wq; dst = wqc;           G = bid - 512; }
    else                { src = wp; dst = wpc;           G = bid - 656; }

    const float* sb = src + (size_t)G * 16 * 768;
#pragma unroll
    for (int k = 0; k < 6; k++) {
        int iv = k * 256 + t;            // 0..1535 (f32x8 runs)
        int row = iv / 96, c8 = iv % 96;
        *(bf16x8*)&L[row][c8 * 8] = cvt8(sb + row * 768 + c8 * 8);
    }
    __syncthreads();
    __bf16* db = dst + (size_t)G * 12288;   // G-stripe: 24 kt x 512, contiguous
#pragma unroll
    for (int k = 0; k < 6; k++) {
        int j = k * 256 + t;             // 0..1535 (bf16x8 runs)
        int r = j & 15, ks = (j >> 4) & 3, kt = j >> 6;
        *(bf16x8*)(db + (size_t)j * 8) = *(const bf16x8*)&L[r][kt * 32 + ks * 8];
    }
}

// legacy scalar tiled convert (only used when ws too small for fused Wp path)
__global__ __launch_bounds__(256)
void cvt_kt(const float* __restrict__ src, __bf16* __restrict__ dst, int nrun) {
    int j = blockIdx.x * 256 + threadIdx.x;
    if (j >= nrun) return;
    const int r  = j & 15;
    const int ks = (j >> 4) & 3;
    const int t2 = j >> 6;
    const int kt = t2 % 24;
    const int G  = t2 / 24;
    *(bf16x8*)(dst + (size_t)j * 8) =
        cvt8(src + (size_t)(G * 16 + r) * 768 + kt * 32 + ks * 8);
}

// ---------------------------------------------------------------------------
// QKV GEMM, 128x128 tile, BK=32, 3-buffer counted-vmcnt pipeline on TILED
// operands (round-7 structure, 57.5us, 0 bank conflicts). Unchanged.
// ---------------------------------------------------------------------------
__global__ __launch_bounds__(256)
void gemm_qkv_s(const __bf16* __restrict__ Xc, const __bf16* __restrict__ Wq,
                const float* __restrict__ bias,
                __bf16* __restrict__ qo, __bf16* __restrict__ ko,
                __bf16* __restrict__ vo)
{
    __shared__ __bf16 As[3][128 * 32];   // 24 KB (8 groups x 512 elems)
    __shared__ __bf16 Bs[3][128 * 32];   // 24 KB

    const int t = threadIdx.x, w = t >> 6, lane = t & 63;
    const int l15 = lane & 15, quad = lane >> 4;
    const int wm = w >> 1, wn = w & 1;

    const int bid  = blockIdx.x;          // 0..1151
    const int xcd  = bid & 7;
    const int i6   = bid >> 3;            // 0..143
    const int pair = i6 / 18;             // 0..7
    const int gx   = i6 - pair * 18;      // 0..17
    const int p    = xcd * 8 + pair;      // 0..63
    const int gy   = p & 31;
    const int st   = p >> 5;

    const __bf16* Ab = Xc + (size_t)st * 3145728 + (size_t)(gy * 8) * 24 * 512;
    const __bf16* Bb = Wq + (size_t)(gx * 8) * 24 * 512;

    f32x4 acc[4][4];
#pragma unroll
    for (int mi = 0; mi < 4; mi++)
#pragma unroll
        for (int ni = 0; ni < 4; ni++) acc[mi][ni] = f32x4{0.f, 0.f, 0.f, 0.f};

    const int ga0 = w * 2, ga1 = w * 2 + 1;     // this wave's groups

#define QSTAGE(BUF, KT)                                                          \
    do {                                                                         \
        async16(Ab + ((size_t)ga0 * 24 + (KT)) * 512 + lane * 8,                 \
                &As[BUF][ga0 * 512 + lane * 8]);                                 \
        async16(Ab + ((size_t)ga1 * 24 + (KT)) * 512 + lane * 8,                 \
                &As[BUF][ga1 * 512 + lane * 8]);                                 \
        async16(Bb + ((size_t)ga0 * 24 + (KT)) * 512 + lane * 8,                 \
                &Bs[BUF][ga0 * 512 + lane * 8]);                                 \
        async16(Bb + ((size_t)ga1 * 24 + (KT)) * 512 + lane * 8,                 \
                &Bs[BUF][ga1 * 512 + lane * 8]);                                 \
    } while (0)

    QSTAGE(0, 0);

#pragma unroll 3
    for (int kt = 0; kt < 24; kt++) {
        const int cb = kt % 3;
        if (kt < 23) {
            QSTAGE((kt + 1) % 3, kt + 1);
            asm volatile("s_waitcnt vmcnt(4)" ::: "memory");  // kt landed; kt+1 in flight
        } else {
            asm volatile("s_waitcnt vmcnt(0)" ::: "memory");  // tail drain
        }
        __builtin_amdgcn_s_barrier();
        __builtin_amdgcn_sched_barrier(0);

        bf16x8 af[4], bfr[4];
#pragma unroll
        for (int mi = 0; mi < 4; mi++)
            af[mi] = *(const bf16x8*)&As[cb][(wm * 4 + mi) * 512 + lane * 8];
#pragma unroll
        for (int ni = 0; ni < 4; ni++)
            bfr[ni] = *(const bf16x8*)&Bs[cb][(wn * 4 + ni) * 512 + lane * 8];
#pragma unroll
        for (int mi = 0; mi < 4; mi++)
#pragma unroll
            for (int ni = 0; ni < 4; ni++)
                acc[mi][ni] = __builtin_amdgcn_mfma_f32_16x16x32_bf16(af[mi], bfr[ni], acc[mi][ni], 0, 0, 0);
    }
#undef QSTAGE

    const int which = (gx * 128) / 768;   // uniform per block (tile never spans)

    if (which == 2) {
#pragma unroll
        for (int ni = 0; ni < 4; ni++) {
            int j = gx * 128 + wn * 64 + ni * 16 + l15;
            int c = j - 1536;
            int h = c >> 6, d = c & 63;
            float bj = bias[j];
#pragma unroll
            for (int mi = 0; mi < 4; mi++) {
                int row0 = gy * 128 + wm * 64 + mi * 16 + quad * 4;
                int b = row0 >> 10, tok0 = row0 & 1023;
                bf16x4 pv;
#pragma unroll
                for (int r = 0; r < 4; r++) pv[r] = (__bf16)(acc[mi][ni][r] + bj);
                *(bf16x4*)&vo[((size_t)((st * 4 + b) * 12 + h) * 64 + d) * 1024 + tok0] = pv;
            }
        }
    } else {
#pragma unroll
        for (int ni = 0; ni < 4; ni++) {
            int j     = gx * 128 + wn * 64 + ni * 16 + l15;   // 0..1535
            int c     = j - which * 768;
            int h = c >> 6, d = c & 63;
            float bj  = bias[j];
#pragma unroll
            for (int mi = 0; mi < 4; mi++) {
#pragma unroll
                for (int r = 0; r < 4; r++) {
                    int row = gy * 128 + wm * 64 + mi * 16 + quad * 4 + r;
                    int b = row >> 10, tok = row & 1023;
                    float val = acc[mi][ni][r] + bj;
                    if (which == 0)
                        qo[((size_t)((st * 4 + b) * 12 + h) * 1024 + tok) * 64 + d] = (__bf16)(val * 0.125f);
                    else
                        ko[((size_t)((st * 4 + b) * 12 + h) * 1024 + tok) * 64 + d] = (__bf16)val;
                }
            }
        }
    }
}

// ---------------------------------------------------------------------------
// proj GEMM, 64x128 tile, BK=32, 3-buffer counted-vmcnt pipeline, TILED
// operands. Grid 6x128 = 768 blocks = EXACTLY 3/CU balanced (old 384-block
// 128x128 grid was 1.5/CU -> 4/3 makespan penalty). 4 waves (2Mx2N), wave
// output 32x64 (acc 2x4). Per-wave stage: 1 A-group + 2 B-groups -> vmcnt(3).
// LDS 36 KB. Race: same 3-buffer ledger as qkv.
// ---------------------------------------------------------------------------
__global__ __launch_bounds__(256)
void gemm_proj(const __bf16* __restrict__ A, const __bf16* __restrict__ Wp,
               const float* __restrict__ bias, float* __restrict__ out)
{
    __shared__ __bf16 As[3][64 * 32];    // 4 KB per buf
    __shared__ __bf16 Bs[3][128 * 32];   // 8 KB per buf

    const int t = threadIdx.x, w = t >> 6, lane = t & 63;
    const int l15 = lane & 15, quad = lane >> 4;
    const int wm = w >> 1, wn = w & 1;
    const int gx = blockIdx.x, gy = blockIdx.y;   // 6 x 128

    const __bf16* Ab = A  + (size_t)(gy * 4) * 24 * 512;
    const __bf16* Bb = Wp + (size_t)(gx * 8) * 24 * 512;

    f32x4 acc[2][4];
#pragma unroll
    for (int mi = 0; mi < 2; mi++)
#pragma unroll
        for (int ni = 0; ni < 4; ni++) acc[mi][ni] = f32x4{0.f, 0.f, 0.f, 0.f};

#define PSTAGE(BUF, KT)                                                          \
    do {                                                                         \
        async16(Ab + ((size_t)w * 24 + (KT)) * 512 + lane * 8,                   \
                &As[BUF][w * 512 + lane * 8]);                                   \
        async16(Bb + ((size_t)(w * 2) * 24 + (KT)) * 512 + lane * 8,             \
                &Bs[BUF][(w * 2) * 512 + lane * 8]);                             \
        async16(Bb + ((size_t)(w * 2 + 1) * 24 + (KT)) * 512 + lane * 8,         \
                &Bs[BUF][(w * 2 + 1) * 512 + lane * 8]);                         \
    } while (0)

    PSTAGE(0, 0);

#pragma unroll 3
    for (int kt = 0; kt < 24; kt++) {
        const int cb = kt % 3;
        if (kt < 23) {
            PSTAGE((kt + 1) % 3, kt + 1);
            asm volatile("s_waitcnt vmcnt(3)" ::: "memory");
        } else {
            asm volatile("s_waitcnt vmcnt(0)" ::: "memory");
        }
        __builtin_amdgcn_s_barrier();
        __builtin_amdgcn_sched_barrier(0);

        bf16x8 af[2], bfr[4];
#pragma unroll
        for (int mi = 0; mi < 2; mi++)
            af[mi] = *(const bf16x8*)&As[cb][(wm * 2 + mi) * 512 + lane * 8];
#pragma unroll
        for (int ni = 0; ni < 4; ni++)
            bfr[ni] = *(const bf16x8*)&Bs[cb][(wn * 4 + ni) * 512 + lane * 8];
#pragma unroll
        for (int mi = 0; mi < 2; mi++)
#pragma unroll
            for (int ni = 0; ni < 4; ni++)
                acc[mi][ni] = __builtin_amdgcn_mfma_f32_16x16x32_bf16(af[mi], bfr[ni], acc[mi][ni], 0, 0, 0);
    }
#undef PSTAGE

#pragma unroll
    for (int ni = 0; ni < 4; ni++) {
        int col  = gx * 128 + wn * 64 + ni * 16 + l15;
        float bj = bias[col];
#pragma unroll
        for (int mi = 0; mi < 2; mi++)
#pragma unroll
            for (int r = 0; r < 4; r++) {
                int row = gy * 64 + (wm * 2 + mi) * 16 + quad * 4 + r;  // 0..8191
                out[(size_t)row * 768 + col] = acc[mi][ni][r] + bj;
            }
    }
}

// ---------------------------------------------------------------------------
// Dual-stream flash attention (unchanged from round 7): 2 waves/block, 2
// q-sets/wave, 32-key tiles, double-buffered; TILED o_ws epilogue.
// ---------------------------------------------------------------------------
__global__ __launch_bounds__(128, 2)
void attn_k(const __bf16* __restrict__ qws, const __bf16* __restrict__ kws,
            const __bf16* __restrict__ vws, __bf16* __restrict__ ows)
{
    __shared__ __bf16 Ks[2][2][2][2][512];  // [buf][s][kk][mi2][lane*8] 16 KB
    __shared__ __bf16 Vs[2][2][4][512];     // [buf][s][mi4][lane*8]     16 KB
    __shared__ __bf16 Ps[2][2][16 * 72];    // [wave][set][row*72]        9 KB

    const int g  = blockIdx.x;
    const int qt = g / 48;              // 0..15
    const int bh = g % 48;              // 0..47
    const int b = bh / 12, h = bh % 12;
    const int t = threadIdx.x, w = t >> 6, lane = t & 63;
    const int l15 = lane & 15, quad = lane >> 4;

    const size_t head_off = (size_t)bh * 65536;          // 1024*64
    const size_t ss       = (size_t)48 * 65536;          // stream stride

    bf16x8 qf[2][2][2];
#pragma unroll
    for (int set = 0; set < 2; set++)
#pragma unroll
        for (int s = 0; s < 2; s++)
#pragma unroll
            for (int kk = 0; kk < 2; kk++)
                qf[set][s][kk] = *(const bf16x8*)(qws + s * ss + head_off
                    + (size_t)(qt * 64 + w * 32 + set * 16 + l15) * 64 + kk * 32 + quad * 8);

    float lsum[2] = {0.f, 0.f};
    f32x4 accO[2][2][4];
#pragma unroll
    for (int set = 0; set < 2; set++)
#pragma unroll
        for (int s = 0; s < 2; s++)
#pragma unroll
            for (int mi = 0; mi < 4; mi++) accO[set][s][mi] = f32x4{0.f, 0.f, 0.f, 0.f};

    const __bf16* kbase = kws + head_off;
    const __bf16* vbase = vws + head_off;

#define STAGE_TILE(BUF, KEYB)                                                   \
    do {                                                                        \
        if (w == 0) {                                                           \
            _Pragma("unroll")                                                   \
            for (int i = 0; i < 8; i++) {                                       \
                const int s = i >> 2, kk = (i >> 1) & 1, mi = i & 1;            \
                async16(kbase + s * ss + (size_t)((KEYB) + mi * 16 + l15) * 64  \
                            + kk * 32 + quad * 8,                               \
                        &Ks[BUF][s][kk][mi][lane * 8]);                         \
            }                                                                   \
        } else {                                                                \
            _Pragma("unroll")                                                   \
            for (int i = 0; i < 8; i++) {                                       \
                const int s = i >> 2, mi = i & 3;                               \
                async16(vbase + s * ss + (size_t)(mi * 16 + l15) * 1024         \
                            + (KEYB) + quad * 8,                                \
                        &Vs[BUF][s][mi][lane * 8]);                             \
            }                                                                   \
        }                                                                       \
    } while (0)

    STAGE_TILE(0, 0);
    __syncthreads();

#pragma unroll 2
    for (int kt = 0; kt < 32; kt++) {
        const int cb = kt & 1, nb = cb ^ 1;

        if (kt < 31) STAGE_TILE(nb, (kt + 1) * 32);

        f32x4 accS[2][2];
#pragma unroll
        for (int set = 0; set < 2; set++)
#pragma unroll
            for (int mi = 0; mi < 2; mi++) accS[set][mi] = f32x4{0.f, 0.f, 0.f, 0.f};
        __builtin_amdgcn_s_setprio(1);
#pragma unroll
        for (int s = 0; s < 2; s++)
#pragma unroll
            for (int kk = 0; kk < 2; kk++) {
                bf16x8 kf0 = *(const bf16x8*)&Ks[cb][s][kk][0][lane * 8];
                bf16x8 kf1 = *(const bf16x8*)&Ks[cb][s][kk][1][lane * 8];
#pragma unroll
                for (int set = 0; set < 2; set++) {
                    accS[set][0] = __builtin_amdgcn_mfma_f32_16x16x32_bf16(kf0, qf[set][s][kk], accS[set][0], 0, 0, 0);
                    accS[set][1] = __builtin_amdgcn_mfma_f32_16x16x32_bf16(kf1, qf[set][s][kk], accS[set][1], 0, 0, 0);
                }
            }
        __builtin_amdgcn_s_setprio(0);

#pragma unroll
        for (int set = 0; set < 2; set++) {
            float rs = 0.f;
#pragma unroll
            for (int mi = 0; mi < 2; mi++) {
                bf16x4 pk;
#pragma unroll
                for (int r = 0; r < 4; r++) {
                    float pv = __expf(accS[set][mi][r]);
                    pk[r] = (__bf16)pv;
                    rs += pv;
                }
                *(bf16x4*)&Ps[w][set][l15 * 72 + mi * 16 + quad * 4] = pk;
            }
            lsum[set] += rs;
        }

        bf16x8 pa0 = *(const bf16x8*)&Ps[w][0][l15 * 72 + quad * 8];
        bf16x8 pa1 = *(const bf16x8*)&Ps[w][1][l15 * 72 + quad * 8];
        __builtin_amdgcn_s_setprio(1);
#pragma unroll
        for (int s = 0; s < 2; s++)
#pragma unroll
            for (int mi = 0; mi < 4; mi++) {
                bf16x8 vf = *(const bf16x8*)&Vs[cb][s][mi][lane * 8];
                accO[0][s][mi] = __builtin_amdgcn_mfma_f32_16x16x32_bf16(vf, pa0, accO[0][s][mi], 0, 0, 0);
                accO[1][s][mi] = __builtin_amdgcn_mfma_f32_16x16x32_bf16(vf, pa1, accO[1][s][mi], 0, 0, 0);
            }
        __builtin_amdgcn_s_setprio(0);

        __syncthreads();
    }
#undef STAGE_TILE

#pragma unroll
    for (int set = 0; set < 2; set++) {
        float l = lsum[set];
        l += __shfl_xor(l, 16);
        l += __shfl_xor(l, 32);
        float il = 1.f / l;

        const int tok = qt * 64 + w * 32 + set * 16 + l15;
#pragma unroll
        for (int s = 0; s < 2; s++)
#pragma unroll
            for (int mi = 0; mi < 4; mi++) {
                bf16x4 ov;
#pragma unroll
                for (int r = 0; r < 4; r++) ov[r] = (__bf16)(accO[set][s][mi][r] * il);
                const int row = (s * 4 + b) * 1024 + tok;
                const int c   = h * 64 + mi * 16 + quad * 4;
                const size_t off = ((size_t)(row >> 4) * 24 + (c >> 5)) * 512
                                 + ((c >> 3) & 3) * 128 + (row & 15) * 8 + (c & 7);
                *(bf16x4*)&ows[off] = ov;
            }
    }
}

// ---------------------------------------------------------------------------
extern "C" void kernel_launch(void* const* d_in, const int* in_sizes, int n_in,
                              void* d_out, int out_size, void* d_ws, size_t ws_size,
                              hipStream_t stream)
{
    const float* x1    = (const float*)d_in[0];
    const float* x2    = (const float*)d_in[1];
    const float* Wqkv  = (const float*)d_in[2];
    const float* bqkv  = (const float*)d_in[3];
    const float* Wproj = (const float*)d_in[4];
    const float* bproj = (const float*)d_in[5];
    float* out = (float*)d_out;

    const size_t qkv_elems = (size_t)2 * 4 * 12 * 1024 * 64;   // 6,291,456
    __bf16* q_ws = (__bf16*)d_ws;
    __bf16* k_ws = q_ws + qkv_elems;
    __bf16* v_ws = k_ws + qkv_elems;
    __bf16* pool = v_ws + qkv_elems;
    __bf16* o_ws = pool;                // 8192*768 tiled (attn out)
    __bf16* Wqc  = pool + 3145728;      // 2304*768 tiled (dead after QKV GEMM)
    __bf16* Xc   = (__bf16*)d_out;      // x1c | x2c tiled (scratch in out buf)

    const bool big = ws_size >= (size_t)(4 * qkv_elems + 589824) * sizeof(__bf16);
    __bf16* Wpc = big ? (pool + qkv_elems)   // past proven footprint
                      : q_ws;                // legacy: q dead after attn

    // 1) fused fp32->bf16 tiled converts via LDS transpose (both sides coalesced)
    cvt4_k<<<big ? 704 : 656, 256, 0, stream>>>(x1, x2, Wqkv, Wproj, Xc, Wqc, Wpc);
    // 2) QKV GEMM, tiled operands, XCD-ownership swizzle, 3-buf counted-vmcnt
    gemm_qkv_s<<<1152, 256, 0, stream>>>(Xc, Wqc, bqkv, q_ws, k_ws, v_ws);
    // 3) attention (tiled o_ws epilogue)
    attn_k<<<768, 128, 0, stream>>>(q_ws, k_ws, v_ws, o_ws);
    // 4) legacy tiled proj weight convert only if ws too small
    if (!big) cvt_kt<<<288, 256, 0, stream>>>(Wproj, Wpc, 73728);
    // 5) proj GEMM, 64x128 tiles, grid 6x128 = 768 = 3/CU balanced
    gemm_proj<<<dim3(6, 128), 256, 0, stream>>>(o_ws, Wpc, bproj, out);
}